// Round 11
// baseline (97.361 us; speedup 1.0000x reference)
//
#include <hip/hip_runtime.h>
#include <math.h>

// Problem constants (reference: N=16384, D=128, T=0.07)
#define NROWS 16384
#define DDIM  128
constexpr float TEMP = 0.07f;
// Pre-scale trick: x *= sqrt(log2(e)/T) so MFMA emits acc = S*<xi,xj> and
// row_lse = ln(sum exp2(acc)). The DIAGONAL (sim_ii = 1 exactly) is masked
// out of the MFMA path and added analytically in finalize. Off-diag is only
// ~2.3% of rowsum, so fp8 e4m3 error there is damped ~44x.
constexpr float S_EXP = 1.44269504088896f / TEMP;  // 20.6099291

typedef __attribute__((ext_vector_type(16))) float f32x16;
typedef __attribute__((ext_vector_type(8)))  int   i32x8;

// Convert + pre-scale to fp8 e4m3, writing the 32x32x64 f8f6f4 FRAGMENT-
// PACKED layout: element (row, k) at byte
//   (panel<<14) | (rb<<12) | (km<<11) | (kh<<10) | (lr<<5) | j
// where panel=row>>7, rb=(row>>5)&3, lr=row&31, km=k>>6, kh=(k>>5)&1,
// j=k&31. MFMA operand layout: lane = kh*32 + lr holds 32 contiguous
// bytes (k = km*64 + kh*32 + j), so a wave's fragment load is ONE
// contiguous 2048 B region (lane*32), fully coalesced. Same buffer serves
// A (row panels) and B (col panels). [r10: verified absmax 0.0]
__global__ void convert_k(const float* __restrict__ x, unsigned char* __restrict__ xbp,
                          float* __restrict__ accum, int* __restrict__ cnt) {
  const float R = 4.53981419f;  // sqrt(S_EXP); |x*R| <= ~1.3, inside e4m3 range
  const int gid = blockIdx.x * blockDim.x + threadIdx.x;
  const int i = gid * 4;
  float4 v = *(const float4*)(x + i);
  int p = __builtin_amdgcn_cvt_pk_fp8_f32(v.x * R, v.y * R, 0, false);
  p = __builtin_amdgcn_cvt_pk_fp8_f32(v.z * R, v.w * R, p, true);
  const int row = i >> 7, k0 = i & 127;
  const int panel = row >> 7, rb = (row >> 5) & 3, lr = row & 31;
  const int km = k0 >> 6, kh = (k0 >> 5) & 1, j = k0 & 31;  // j 4-aligned
  *(int*)(xbp + ((size_t)panel << 14) + (rb << 12) + (km << 11) + (kh << 10) +
          (lr << 5) + j) = p;
  if (gid == 0) { *accum = 0.f; *cnt = 0; }
}

// Triangular Gram — ROUND-11: r10's MX-scaled 32x32x64 path (total 104.9
// -> 97.1 us, gram ~42) + REGISTER PING-PONG PREFETCH at (ti,cb2)-job
// granularity. The tile loop flattens to 2*ntiles homogeneous jobs
// (ti=jj>>1, cb2=jj&1); while job jj computes (2 chained MFMA + 16 exp),
// job jj+1's B-pair is already in flight in the other named register
// buffer (2-step unrolled body -> all reg indices static, rule #20).
// Hides the per-job L2 load latency (~200-400 cyc) that the zero-barrier
// loop still exposed serially. VGPR ~110-120, must stay <=128.
// r8/r9 structure retained: zero barriers in the loop, per-(tile,wave)
// private csbuf slots, col-split 256-thr blocks (I,ci,s); wave w owns
// rows w*32, cols ci*64. d-tiles s==0: d=0..8 else 8s+1..8s+8;
// J=(I+d)%128. d==0 diag masked; d in {0,64} col-slices skipped (mirror).
// C/D layout 32x32: col = lane&31, row = (reg&3)+8*(reg>>2)+4*(lane>>5).
__global__ __launch_bounds__(256, 4)
void gram_tri_k(const unsigned char* __restrict__ xbp, float* __restrict__ rowpart,
                float* __restrict__ colpart) {
  __shared__ float csbuf[9][4][64];  // 9 KB: per-(tile,wave) col partials

  const int tid = threadIdx.x;
  const int w = tid >> 6, lane = tid & 63;
  const int l31 = lane & 31, lh = lane >> 5;
  const int I = (int)(blockIdx.x >> 4);
  const int ci = (int)((blockIdx.x >> 3) & 1);
  const int s = (int)(blockIdx.x & 7);
  const int rI = I * 128;
  const int dstart = (s == 0) ? 0 : 8 * s + 1;
  const int ntiles = (s == 0) ? 9 : 8;
  const int njobs = ntiles * 2;  // always even

  // A frags: rows w*32..w*32+31 of panel I; lane holds 32 B at lane*32
  i32x8 af[2];
  const unsigned char* gAb = xbp + ((size_t)I << 14) + (w << 12) + (lane << 5);
#pragma unroll
  for (int km = 0; km < 2; ++km)
    af[km] = *(const i32x8*)(gAb + (km << 11));

  // B lane base: col-tile (ci*2 + cb2) of panel J
  const unsigned char* gBlane = xbp + ((ci * 2) << 12) + (lane << 5);

  float rs[16];
#pragma unroll
  for (int r = 0; r < 16; ++r) rs[r] = 0.f;

  // B load for job jj (guarded past-end prefetch leaves regs unused)
  auto loadB = [&](i32x8& d0, i32x8& d1, int jj) {
    if (jj < njobs) {
      const unsigned char* p = gBlane +
          ((size_t)((I + dstart + (jj >> 1)) & 127) << 14) + ((jj & 1) << 12);
      d0 = *(const i32x8*)p;
      d1 = *(const i32x8*)(p + 2048);
    }
  };
  // compute job jj from a B-pair already in registers
  auto computeJ = [&](const i32x8& b0, const i32x8& b1, int jj) {
    const int ti = jj >> 1, cb2 = jj & 1;
    const bool dz = (dstart + ti == 0);  // uniform; only s==0 pays the mask
    f32x16 a;
#pragma unroll
    for (int z = 0; z < 16; ++z) a[z] = 0.f;
    a = __builtin_amdgcn_mfma_scale_f32_32x32x64_f8f6f4(
        af[0], b0, a, 0 /*cbsz: fp8*/, 0 /*blgp: fp8*/, 0, 127, 0, 127);
    a = __builtin_amdgcn_mfma_scale_f32_32x32x64_f8f6f4(
        af[1], b1, a, 0, 0, 0, 127, 0, 127);
    float cst = 0.f;
#pragma unroll
    for (int r = 0; r < 16; ++r) {
      float e = __builtin_amdgcn_exp2f(a[r]);
      if (dz && (w * 32 + (r & 3) + 8 * (r >> 2) + 4 * lh) ==
                    (ci * 64 + cb2 * 32 + l31))
        e = 0.f;  // mask diagonal
      rs[r] += e;
      cst += e;
    }
    // col-sum: lane covers 16 rows of col l31; opposite lane-half has the
    // other 16 -> one xor-32 shuffle completes the column.
    cst += __shfl_xor(cst, 32, 64);
    if (lh == 0) csbuf[ti][w][cb2 * 32 + l31] = cst;
  };

  i32x8 bA0, bA1, bB0, bB1;
  loadB(bA0, bA1, 0);
  for (int jj = 0; jj < njobs; jj += 2) {
    loadB(bB0, bB1, jj + 1);   // prefetch next job (always valid: njobs even)
    computeJ(bA0, bA1, jj);
    loadB(bA0, bA1, jj + 2);   // prefetch job after next (guarded)
    computeJ(bB0, bB1, jj + 1);
  }

  // row-sums: rs[r] on lane l = partials of row (r&3)+8*(r>>2)+4*lh over
  // cols {l31, 32+l31}; reduce across the 32 lanes of each lane-half.
#pragma unroll
  for (int m = 1; m <= 16; m <<= 1)
#pragma unroll
    for (int r = 0; r < 16; ++r) rs[r] += __shfl_xor(rs[r], m, 64);
  if (l31 == 0) {
#pragma unroll
    for (int r = 0; r < 16; ++r)
      rowpart[(size_t)(ci * 8 + s) * NROWS + rI + w * 32 + (r & 3) + 8 * (r >> 2) +
              4 * lh] = rs[r];
  }

  __syncthreads();  // THE ONLY barrier: all csbuf slots complete

  // colpart stores: (ti, col) over this block's 64 cols, d not in {0,64}
  for (int e = tid; e < ntiles * 64; e += 256) {
    const int ti = e >> 6, col = e & 63;
    const int d = dstart + ti;
    if (d != 0 && d != 64)
      colpart[(size_t)(d - 1) * NROWS + ((I + d) & 127) * 128 + ci * 64 + col] =
          csbuf[ti][0][col] + csbuf[ti][1][col] + csbuf[ti][2][col] + csbuf[ti][3][col];
  }
}

// 64 blocks x 64 threads, 4 rows/thread via float4: sums 16 rowpart +
// 63 colpart slices, adds the analytic diagonal 2^S, logs, wave-reduces.
__global__ void finalize_k(const float* __restrict__ rowpart, const float* __restrict__ colpart,
                           float* __restrict__ accum, int* __restrict__ cnt,
                           float* __restrict__ out) {
  const int tid = threadIdx.x;
  const size_t i4 = (size_t)(blockIdx.x * 64 + tid) * 4;
  const float DIAG = __builtin_exp2f(S_EXP);  // exact e^{1/T}, rows unit-norm
  float4 v = {DIAG, DIAG, DIAG, DIAG};
#pragma unroll
  for (int s2 = 0; s2 < 16; ++s2) {
    float4 t = *(const float4*)&rowpart[(size_t)s2 * NROWS + i4];
    v.x += t.x; v.y += t.y; v.z += t.z; v.w += t.w;
  }
#pragma unroll
  for (int d = 1; d < 64; ++d) {
    float4 t = *(const float4*)&colpart[(size_t)(d - 1) * NROWS + i4];
    v.x += t.x; v.y += t.y; v.z += t.z; v.w += t.w;
  }
  float sm = __logf(v.x) + __logf(v.y) + __logf(v.z) + __logf(v.w);
#pragma unroll
  for (int m = 1; m < 64; m <<= 1) sm += __shfl_xor(sm, m, 64);
  if (tid == 0) {
    atomicAdd(accum, sm);
    __threadfence();
    int prev = atomicAdd(cnt, 1);
    if (prev == (int)gridDim.x - 1) {
      __threadfence();
      float a = __hip_atomic_load(accum, __ATOMIC_RELAXED, __HIP_MEMORY_SCOPE_AGENT);
      out[0] = a / (float)NROWS;
    }
  }
}

extern "C" void kernel_launch(void* const* d_in, const int* in_sizes, int n_in,
                              void* d_out, int out_size, void* d_ws, size_t ws_size,
                              hipStream_t stream) {
  const float* x = (const float*)d_in[0];
  float* out = (float*)d_out;
  // ws layout: xbp 2 MB (fp8, fragment-packed) | rowpart 16x64KB | colpart 63x64KB | accum,cnt
  unsigned char* xbp = (unsigned char*)d_ws;
  float* rowpart = (float*)((char*)d_ws + (size_t)NROWS * DDIM);
  float* colpart = rowpart + (size_t)16 * NROWS;
  float* accum = colpart + (size_t)63 * NROWS;
  int* cnt = (int*)(accum + 1);

  convert_k<<<NROWS * DDIM / (256 * 4), 256, 0, stream>>>(x, xbp, accum, cnt);
  gram_tri_k<<<128 * 16, 256, 0, stream>>>(xbp, rowpart, colpart);
  finalize_k<<<NROWS / 256, 64, 0, stream>>>(rowpart, colpart, accum, cnt, out);
}